// Round 12
// baseline (559.015 us; speedup 1.0000x reference)
//
#include <hip/hip_runtime.h>
#include <hip/hip_bf16.h>
#include <stdint.h>

#define NROWS   65536
#define GR      16                // rows per group
#define NG      16                // groups per block
#define RPB     (GR*NG)           // 256 rows per block (contiguous output region)
#define NBLK    (NROWS/RPB)       // 256 blocks = 1 per CU
#define TPB     1024
#define H2N     100
#define KPAD    128
#define N3      1224
#define OUTW    2193
#define TAILN   969
#define T1OFF   77
#define NTILE   138               // 77 main + 61 pair slots
#define NTOT    199               // frag tiles in w3f
#define PCOLS   2208              // virtual cols
#define PSTRC   2212              // panel row stride (bank-friendly)
#define NCHUNK  9                 // 9 x 256 cols per row dump

typedef __attribute__((ext_vector_type(8))) short bf16x8;
typedef __attribute__((ext_vector_type(4))) float f32x4;
typedef __attribute__((ext_vector_type(4))) unsigned short u16x4;

__device__ __forceinline__ float fast_sigmoid(float z){
    return __builtin_amdgcn_rcpf(1.0f + __expf(-z));
}
__device__ __forceinline__ unsigned short f2bf(float v){
    __hip_bfloat16 h = __float2bfloat16(v);
    return *reinterpret_cast<unsigned short*>(&h);
}
__device__ __forceinline__ void store16(float* p, f32x4 v){
    __builtin_memcpy(p, &v, 16);
}

// w3f[((t*4+ks)*64+lane)*8+e] = bf16(W3[k][srccol]) with bias folded at k==100.
// frag tiles: 0..76 main; 77..137 gathered c1; 138..198 gathered c2.
__global__ void prep_kernel(const float* __restrict__ W3,
                            const float* __restrict__ b3,
                            const float* __restrict__ wgt,
                            const int* __restrict__ idx1,
                            const int* __restrict__ idx2,
                            unsigned short* __restrict__ w3f,
                            float* __restrict__ pwf){
    const int t    = blockIdx.x;
    const int ks   = threadIdx.x >> 6;
    const int lane = threadIdx.x & 63;
    const int lm   = lane & 15, lgf = lane >> 4;

    int col = -1;
    if (t < T1OFF){
        int c = t * 16 + lm;
        if (c < N3) col = c;
    } else if (t < NTILE){
        int p = (t - T1OFF) * 16 + lm;
        if (p < TAILN){ int j = p / 17; col = idx1[j] * 17 + (p - j * 17); }
    } else {
        int p = (t - NTILE) * 16 + lm;
        if (p < TAILN){ int j = p / 17; col = idx2[j] * 17 + (p - j * 17); }
    }

    unsigned short vals[8];
    #pragma unroll
    for (int e = 0; e < 8; ++e){
        int k = ks * 32 + lgf * 8 + e;
        float v = 0.0f;
        if (col >= 0){
            if (k < H2N)       v = W3[k * N3 + col];
            else if (k == H2N) v = b3[col];          // bias folded into K
        }
        vals[e] = f2bf(v);
    }
    *reinterpret_cast<bf16x8*>(w3f + ((size_t)(t * 4 + ks) * 64 + lane) * 8)
        = *reinterpret_cast<bf16x8*>(vals);

    if (ks == 0 && lgf == 1 && t >= T1OFF && t < NTILE){
        int p = (t - T1OFF) * 16 + lm;
        pwf[(t - T1OFF) * 16 + lm] = (p < TAILN) ? wgt[p / 17] : 0.0f;
    }
}

__global__ __launch_bounds__(TPB, 4)
void snn_kernel(const float* __restrict__ x,
                const float* __restrict__ W1, const float* __restrict__ b1,
                const float* __restrict__ W2, const float* __restrict__ b2,
                const unsigned short* __restrict__ w3f,
                const float* __restrict__ pwf,
                float* __restrict__ out)
{
    __shared__ __align__(16) unsigned short panel[2][GR][PSTRC];  // 141.6 KB
    __shared__ __align__(16) unsigned short h2b[2][GR][KPAD];     // 8 KB
    __shared__ float h1s[GR][10];
    __shared__ float w2s[H2N * 10];
    __shared__ float b2s[H2N];

    const int t = threadIdx.x, lane = t & 63, wid = t >> 6;   // 16 waves
    const int lm = lane & 15, lg = lane >> 4;
    const unsigned int rowblk = blockIdx.x * RPB;

    // W1/b1 per-thread regs (j = t%10)
    const int jj = t % 10;
    const float w1r = W1[jj], b1r = b1[jj];

    // ---- block prologue: stage W2/b2, h1(0), h2(0)
    for (int i = t; i < H2N * 10; i += TPB) w2s[i] = W2[i];
    if (t < H2N) b2s[t] = b2[t];
    if (t < GR * 10){
        int r = t / 10;
        h1s[r][jj] = fast_sigmoid(x[rowblk + r] * w1r + b1r);
    }
    __syncthreads();
    #pragma unroll
    for (int ii = 0; ii < 2; ++ii){
        int i = t + ii * TPB;
        int r = i >> 7, c = i & 127;
        float v = 0.0f;
        if (c < H2N){
            float z = b2s[c];
            #pragma unroll
            for (int j = 0; j < 10; ++j) z += h1s[r][j] * w2s[j * H2N + c];
            v = fast_sigmoid(z);
        } else if (c == H2N) v = 1.0f;               // bias lane
        h2b[0][r][c] = f2bf(v);
    }
    __syncthreads();

    #define LOADFRAG(dst, tile) do {                                              \
        const unsigned short* bp_ = w3f + ((size_t)((tile) * 4) * 64 + lane) * 8; \
        _Pragma("unroll")                                                         \
        for (int ks_ = 0; ks_ < 4; ++ks_)                                         \
            dst[ks_] = *reinterpret_cast<const bf16x8*>(bp_ + (size_t)ks_ * 512); \
    } while(0)

    auto DUMPCHUNK = [&](int buf, unsigned int drow, int i){
        const int vb = i * 256 + (lane << 2);
        int mode = 0, real = 0;
        if (vb <= 1220)                    { mode = 1; real = vb; }
        else if (vb >= 1232 && vb <= 2196) { mode = 1; real = vb - 8; }
        else if (vb == 2200)               { mode = 2; real = 2192; }
        if (mode){
            const unsigned short* pp = &panel[buf][wid][vb];
            f32x4 v;
            #pragma unroll
            for (int e = 0; e < 4; ++e)
                v[e] = __uint_as_float(((unsigned)pp[e]) << 16);
            float* dst = out + (size_t)drow * OUTW + real;
            if (mode == 1) store16(dst, v);
            else           dst[0] = v[0];
        }
    };

    // ---- main pipelined loop over 16 groups
    for (int g = 0; g < NG; ++g){
        const int cb = g & 1, nb = cb ^ 1;

        // h1(g+1)
        if (g + 1 < NG && t < GR * 10){
            int r = t / 10;
            h1s[r][jj] = fast_sigmoid(x[rowblk + (g + 1) * GR + r] * w1r + b1r);
        }
        __syncthreads();                                   // B1
        // h2(g+1)
        if (g + 1 < NG){
            #pragma unroll
            for (int ii = 0; ii < 2; ++ii){
                int i = t + ii * TPB;
                int r = i >> 7, c = i & 127;
                float v = 0.0f;
                if (c < H2N){
                    float z = b2s[c];
                    #pragma unroll
                    for (int j = 0; j < 10; ++j) z += h1s[r][j] * w2s[j * H2N + c];
                    v = fast_sigmoid(z);
                } else if (c == H2N) v = 1.0f;
                h2b[nb][r][c] = f2bf(v);
            }
        }
        __syncthreads();                                   // B2 (drains prev dump stores)

        bf16x8 hfr[4];
        #pragma unroll
        for (int ks = 0; ks < 4; ++ks)
            hfr[ks] = *reinterpret_cast<const bf16x8*>(&h2b[cb][lm][ks * 32 + lg * 8]);

        const unsigned int drow = rowblk + (g - 1) * GR + wid;   // used only when g>=1

        bf16x8 f1c[4], f1n[4];
        f32x4 wvc = {0,0,0,0}, wvn = {0,0,0,0};
        LOADFRAG(f1c, wid);                                 // slot 0 (always main)
        for (int i = 0; i < NCHUNK; ++i){
            const int s  = wid + (i << 4);
            const int sn = s + 16;
            // 1. prefetch next slot (loads BEFORE stores -> vmcnt decoupling)
            if (sn < NTILE){
                LOADFRAG(f1n, sn);
                if (sn >= T1OFF)
                    wvn = *reinterpret_cast<const f32x4*>(&pwf[(sn - T1OFF) * 16 + (lg << 2)]);
            }
            const bool valid = (s < NTILE);
            const bool pair  = valid && (s >= T1OFF);
            bf16x8 f2[4];
            if (pair) LOADFRAG(f2, s + 61);                 // second side, still before stores
            // 2. one dump chunk of previous group's panel (fire-and-forget)
            if (g >= 1) DUMPCHUNK(nb, drow, i);
            // 3. compute slot
            if (valid){
                f32x4 a1 = {0,0,0,0};
                #pragma unroll
                for (int ks = 0; ks < 4; ++ks)
                    a1 = __builtin_amdgcn_mfma_f32_16x16x32_bf16(f1c[ks], hfr[ks], a1, 0, 0, 0);
                unsigned short o[4];
                if (!pair){
                    #pragma unroll
                    for (int r = 0; r < 4; ++r) o[r] = f2bf(fast_sigmoid(a1[r]));
                } else {
                    f32x4 a2 = {0,0,0,0};
                    #pragma unroll
                    for (int ks = 0; ks < 4; ++ks)
                        a2 = __builtin_amdgcn_mfma_f32_16x16x32_bf16(f2[ks], hfr[ks], a2, 0, 0, 0);
                    #pragma unroll
                    for (int r = 0; r < 4; ++r){
                        float u1 = fast_sigmoid(a1[r]);
                        float u2 = fast_sigmoid(a2[r]);
                        o[r] = f2bf(fmaf(wvc[r], u1 - u2, u2));
                    }
                }
                *reinterpret_cast<u16x4*>(&panel[cb][lm][(s << 4) + (lg << 2)]) =
                    *reinterpret_cast<u16x4*>(o);
            }
            #pragma unroll
            for (int k2 = 0; k2 < 4; ++k2) f1c[k2] = f1n[k2];
            wvc = wvn;
        }
    }

    // ---- epilogue: dump last group
    __syncthreads();
    {
        const unsigned int drow = rowblk + (NG - 1) * GR + wid;
        for (int i = 0; i < NCHUNK; ++i)
            DUMPCHUNK((NG - 1) & 1, drow, i);
    }
    #undef LOADFRAG
}

extern "C" void kernel_launch(void* const* d_in, const int* in_sizes, int n_in,
                              void* d_out, int out_size, void* d_ws, size_t ws_size,
                              hipStream_t stream)
{
    const float* x   = (const float*)d_in[0];
    const float* W1  = (const float*)d_in[1];
    const float* b1  = (const float*)d_in[2];
    const float* W2  = (const float*)d_in[3];
    const float* b2  = (const float*)d_in[4];
    const float* W3  = (const float*)d_in[5];
    const float* b3  = (const float*)d_in[6];
    const float* wgt = (const float*)d_in[7];
    const int*   i1  = (const int*)d_in[8];
    const int*   i2  = (const int*)d_in[9];
    float* out = (float*)d_out;

    unsigned char* ws = (unsigned char*)d_ws;
    unsigned short* w3f = (unsigned short*)ws;                 // 815,104 B
    float*          pwf = (float*)(ws + 815104);               // 3,904 B

    prep_kernel<<<NTOT, 256, 0, stream>>>(W3, b3, wgt, i1, i2, w3f, pwf);
    snn_kernel<<<NBLK, TPB, 0, stream>>>(x, W1, b1, W2, b2, w3f, pwf, out);
}

// Round 13
// 204.475 us; speedup vs baseline: 2.7339x; 2.7339x over previous
//
#include <hip/hip_runtime.h>
#include <hip/hip_bf16.h>
#include <stdint.h>

#define NROWS   65536
#define GR      16                // rows per block
#define NBLK    (NROWS/GR)        // 4096
#define TPB     512
#define H2N     100
#define KPAD    128
#define N3      1224
#define OUTW    2193
#define TAILN   969
#define T1OFF   77
#define NTILE   138               // 77 main + 61 pair slots
#define NTOT    199               // frag tiles in w3f
#define PSTRC   2212              // panel row stride (shorts)

typedef __attribute__((ext_vector_type(8))) short bf16x8;
typedef __attribute__((ext_vector_type(4))) float f32x4;
typedef __attribute__((ext_vector_type(4))) unsigned short u16x4;

__device__ __forceinline__ float fast_sigmoid(float z){
    return __builtin_amdgcn_rcpf(1.0f + __expf(-z));
}
__device__ __forceinline__ unsigned short f2bf(float v){
    __hip_bfloat16 h = __float2bfloat16(v);
    return *reinterpret_cast<unsigned short*>(&h);
}
__device__ __forceinline__ void store16(float* p, f32x4 v){
    __builtin_memcpy(p, &v, 16);
}

// w3f[((t*4+ks)*64+lane)*8+e] = bf16(W3[k][srccol]) with b3 folded at k==100.
// frag tiles: 0..76 main; 77..137 gathered c1; 138..198 gathered c2.
__global__ void prep_kernel(const float* __restrict__ W3,
                            const float* __restrict__ b3,
                            const float* __restrict__ wgt,
                            const int* __restrict__ idx1,
                            const int* __restrict__ idx2,
                            unsigned short* __restrict__ w3f,
                            float* __restrict__ pwf){
    const int t    = blockIdx.x;
    const int ks   = threadIdx.x >> 6;
    const int lane = threadIdx.x & 63;
    const int lm   = lane & 15, lgf = lane >> 4;

    int col = -1;
    if (t < T1OFF){
        int c = t * 16 + lm;
        if (c < N3) col = c;
    } else if (t < NTILE){
        int p = (t - T1OFF) * 16 + lm;
        if (p < TAILN){ int j = p / 17; col = idx1[j] * 17 + (p - j * 17); }
    } else {
        int p = (t - NTILE) * 16 + lm;
        if (p < TAILN){ int j = p / 17; col = idx2[j] * 17 + (p - j * 17); }
    }

    unsigned short vals[8];
    #pragma unroll
    for (int e = 0; e < 8; ++e){
        int k = ks * 32 + lgf * 8 + e;
        float v = 0.0f;
        if (col >= 0){
            if (k < H2N)       v = W3[k * N3 + col];
            else if (k == H2N) v = b3[col];          // bias folded into K
        }
        vals[e] = f2bf(v);
    }
    *reinterpret_cast<bf16x8*>(w3f + ((size_t)(t * 4 + ks) * 64 + lane) * 8)
        = *reinterpret_cast<bf16x8*>(vals);

    if (ks == 0 && lgf == 1 && t >= T1OFF && t < NTILE){
        int p = (t - T1OFF) * 16 + lm;
        pwf[(t - T1OFF) * 16 + lm] = (p < TAILN) ? wgt[p / 17] : 0.0f;
    }
}

__global__ __launch_bounds__(TPB, 4)
void snn_kernel(const float* __restrict__ x,
                const float* __restrict__ W1, const float* __restrict__ b1,
                const float* __restrict__ W2, const float* __restrict__ b2,
                const unsigned short* __restrict__ w3f,
                const float* __restrict__ pwf,
                float* __restrict__ out)
{
    __shared__ __align__(16) unsigned short panel[GR][PSTRC];   // 70.8 KB
    __shared__ __align__(16) unsigned short h2b[GR][KPAD];      // 4 KB
    __shared__ float h1s[GR][10];                               // 640 B
    __shared__ float w2s[H2N * 10];                             // 4 KB
    __shared__ float b2s[H2N];                                  // 400 B

    const int t = threadIdx.x, lane = t & 63, wid = t >> 6;     // 8 waves
    const int lm = lane & 15, lg = lane >> 4;
    const unsigned int rowblk = blockIdx.x * GR;

    // ---- prologue: stage W2/b2, compute h1, h2 (k=100 bias lane = 1.0)
    for (int i = t; i < H2N * 10; i += TPB) w2s[i] = W2[i];
    if (t < H2N) b2s[t] = b2[t];
    if (t < GR * 10){
        int r = t / 10, j = t - r * 10;
        h1s[r][j] = fast_sigmoid(x[rowblk + r] * W1[j] + b1[j]);
    }
    __syncthreads();
    #pragma unroll
    for (int k = 0; k < 4; ++k){
        int i = t + k * TPB;                 // 2048 = 16 x 128
        int r = i >> 7, c = i & 127;
        float v = 0.0f;
        if (c < H2N){
            float z = b2s[c];
            #pragma unroll
            for (int j = 0; j < 10; ++j) z += h1s[r][j] * w2s[j * H2N + c];
            v = fast_sigmoid(z);
        } else if (c == H2N) v = 1.0f;       // bias lane
        h2b[r][c] = f2bf(v);
    }
    __syncthreads();

    bf16x8 hfr[4];
    #pragma unroll
    for (int ks = 0; ks < 4; ++ks)
        hfr[ks] = *reinterpret_cast<const bf16x8*>(&h2b[lm][ks * 32 + lg * 8]);

    #define LOADFRAG(dst, tile) do {                                              \
        const unsigned short* bp_ = w3f + ((size_t)((tile) * 4) * 64 + lane) * 8; \
        _Pragma("unroll")                                                         \
        for (int ks_ = 0; ks_ < 4; ++ks_)                                         \
            dst[ks_] = *reinterpret_cast<const bf16x8*>(bp_ + (size_t)ks_ * 512); \
    } while(0)

    // ---- compute: waves partition 138 slots disjointly; w3f read ONCE per block
    bf16x8 f1c[4], f1n[4];
    f32x4 wvc = {0,0,0,0}, wvn = {0,0,0,0};
    LOADFRAG(f1c, wid);                      // wid <= 7 -> always a main slot
    for (int it = 0; it < 18; ++it){
        const int s  = wid + (it << 3);
        const int sn = s + 8;
        if (sn < NTILE){
            LOADFRAG(f1n, sn);
            if (sn >= T1OFF)
                wvn = *reinterpret_cast<const f32x4*>(&pwf[(sn - T1OFF) * 16 + (lg << 2)]);
        }
        if (s < NTILE){
            const bool pair = (s >= T1OFF);
            bf16x8 f2[4];
            if (pair) LOADFRAG(f2, s + 61);
            f32x4 a1 = {0,0,0,0};
            #pragma unroll
            for (int ks = 0; ks < 4; ++ks)
                a1 = __builtin_amdgcn_mfma_f32_16x16x32_bf16(f1c[ks], hfr[ks], a1, 0, 0, 0);
            unsigned short o[4];
            if (!pair){
                #pragma unroll
                for (int r = 0; r < 4; ++r) o[r] = f2bf(fast_sigmoid(a1[r]));
            } else {
                f32x4 a2 = {0,0,0,0};
                #pragma unroll
                for (int ks = 0; ks < 4; ++ks)
                    a2 = __builtin_amdgcn_mfma_f32_16x16x32_bf16(f2[ks], hfr[ks], a2, 0, 0, 0);
                #pragma unroll
                for (int r = 0; r < 4; ++r){
                    float u1 = fast_sigmoid(a1[r]);
                    float u2 = fast_sigmoid(a2[r]);
                    o[r] = f2bf(fmaf(wvc[r], u1 - u2, u2));
                }
            }
            *reinterpret_cast<u16x4*>(&panel[lm][(s << 4) + (lg << 2)]) =
                *reinterpret_cast<u16x4*>(o);
        }
        #pragma unroll
        for (int k2 = 0; k2 < 4; ++k2) f1c[k2] = f1n[k2];
        wvc = wvn;
    }
    __syncthreads();

    // ---- dump: each wave writes 2 FULL rows, 8.7 KB contiguous each
    #pragma unroll
    for (int rr = 0; rr < 2; ++rr){
        const int row = (wid << 1) + rr;
        float* orow = out + (size_t)(rowblk + row) * OUTW;
        #pragma unroll
        for (int ch = 0; ch < 9; ++ch){
            const int rc = ch * 256 + (lane << 2);     // real col base (mult of 4)
            if (rc <= 2188){
                const int vc = rc + (rc >= N3 ? 8 : 0);
                const unsigned short* pp = &panel[row][vc];
                f32x4 v;
                #pragma unroll
                for (int e = 0; e < 4; ++e)
                    v[e] = __uint_as_float(((unsigned)pp[e]) << 16);
                store16(orow + rc, v);
            } else if (rc == 2192){
                orow[rc] = __uint_as_float(((unsigned)panel[row][rc + 8]) << 16);
            }
        }
    }
    #undef LOADFRAG
}

extern "C" void kernel_launch(void* const* d_in, const int* in_sizes, int n_in,
                              void* d_out, int out_size, void* d_ws, size_t ws_size,
                              hipStream_t stream)
{
    const float* x   = (const float*)d_in[0];
    const float* W1  = (const float*)d_in[1];
    const float* b1  = (const float*)d_in[2];
    const float* W2  = (const float*)d_in[3];
    const float* b2  = (const float*)d_in[4];
    const float* W3  = (const float*)d_in[5];
    const float* b3  = (const float*)d_in[6];
    const float* wgt = (const float*)d_in[7];
    const int*   i1  = (const int*)d_in[8];
    const int*   i2  = (const int*)d_in[9];
    float* out = (float*)d_out;

    unsigned char* ws = (unsigned char*)d_ws;
    unsigned short* w3f = (unsigned short*)ws;                 // 815,104 B
    float*          pwf = (float*)(ws + 815104);               // 3,904 B

    prep_kernel<<<NTOT, 256, 0, stream>>>(W3, b3, wgt, i1, i2, w3f, pwf);
    snn_kernel<<<NBLK, TPB, 0, stream>>>(x, W1, b1, W2, b2, w3f, pwf, out);
}

// Round 14
// 150.460 us; speedup vs baseline: 3.7154x; 1.3590x over previous
//
#include <hip/hip_runtime.h>
#include <hip/hip_bf16.h>
#include <stdint.h>

#define NROWS   65536
#define GR      16                // rows per block
#define NBLK    (NROWS/GR)        // 4096
#define TPB     512
#define H2N     100
#define KPAD    128
#define N3      1224
#define OUTW    2193
#define TAILN   969
#define NMAIN   77                // main tiles only in w3f
#define PSTRC   2212              // panel row stride (shorts)

typedef __attribute__((ext_vector_type(8))) short bf16x8;
typedef __attribute__((ext_vector_type(4))) float f32x4;
typedef __attribute__((ext_vector_type(4))) unsigned short u16x4;

__device__ __forceinline__ float fast_sigmoid(float z){
    return __builtin_amdgcn_rcpf(1.0f + __expf(-z));
}
__device__ __forceinline__ unsigned short f2bf(float v){
    __hip_bfloat16 h = __float2bfloat16(v);
    return *reinterpret_cast<unsigned short*>(&h);
}
__device__ __forceinline__ float bf2f(unsigned short u){
    return __uint_as_float(((unsigned)u) << 16);
}
__device__ __forceinline__ void store16(float* p, f32x4 v){
    __builtin_memcpy(p, &v, 16);
}

// blocks 0..76: w3f[((t*4+ks)*64+lane)*8+e] = bf16(W3[k][t*16+lm]), b3 folded at k==100.
// blocks 77..80: tail tables pk[p]=(c2<<16)|c1, pw[p]=w[j].
__global__ void prep_kernel(const float* __restrict__ W3,
                            const float* __restrict__ b3,
                            const float* __restrict__ wgt,
                            const int* __restrict__ idx1,
                            const int* __restrict__ idx2,
                            unsigned short* __restrict__ w3f,
                            unsigned int* __restrict__ pk,
                            float* __restrict__ pw){
    const int blk = blockIdx.x;
    if (blk < NMAIN){
        const int ks   = threadIdx.x >> 6;
        const int lane = threadIdx.x & 63;
        const int lm   = lane & 15, lgf = lane >> 4;
        const int c    = blk * 16 + lm;
        const bool ok  = (c < N3);

        unsigned short vals[8];
        #pragma unroll
        for (int e = 0; e < 8; ++e){
            int k = ks * 32 + lgf * 8 + e;
            float v = 0.0f;
            if (ok){
                if (k < H2N)       v = W3[k * N3 + c];
                else if (k == H2N) v = b3[c];          // bias folded into K
            }
            vals[e] = f2bf(v);
        }
        *reinterpret_cast<bf16x8*>(w3f + ((size_t)(blk * 4 + ks) * 64 + lane) * 8)
            = *reinterpret_cast<bf16x8*>(vals);
    } else {
        const int p = (blk - NMAIN) * 256 + threadIdx.x;
        if (p < TAILN){
            int j = p / 17, k = p - j * 17;
            unsigned int c1 = (unsigned)(idx1[j] * 17 + k);
            unsigned int c2 = (unsigned)(idx2[j] * 17 + k);
            pk[p] = (c2 << 16) | c1;
            pw[p] = wgt[j];
        }
    }
}

__global__ __launch_bounds__(TPB, 4)
void snn_kernel(const float* __restrict__ x,
                const float* __restrict__ W1, const float* __restrict__ b1,
                const float* __restrict__ W2, const float* __restrict__ b2,
                const unsigned short* __restrict__ w3f,
                const unsigned int* __restrict__ pk,
                const float* __restrict__ pw,
                float* __restrict__ out)
{
    __shared__ __align__(16) unsigned short panel[GR][PSTRC];   // 70.8 KB
    __shared__ __align__(16) unsigned short h2b[GR][KPAD];      // 4 KB
    __shared__ float h1s[GR][10];                               // 640 B
    __shared__ float w2s[H2N * 10];                             // 4 KB
    __shared__ float b2s[H2N];                                  // 400 B

    const int t = threadIdx.x, lane = t & 63, wid = t >> 6;     // 8 waves
    const int lm = lane & 15, lg = lane >> 4;
    const unsigned int rowblk = blockIdx.x * GR;

    // ---- per-thread tail constants (2 entries each; 512*2 >= 969)
    unsigned int tpk[2] = {0, 0}; float tpw[2] = {0.f, 0.f};
    #pragma unroll
    for (int i = 0; i < 2; ++i){
        int p = t + i * TPB;
        if (p < TAILN){ tpk[i] = pk[p]; tpw[i] = pw[p]; }
    }

    // ---- prologue: stage W2/b2, compute h1, h2 (k=100 bias lane = 1.0)
    for (int i = t; i < H2N * 10; i += TPB) w2s[i] = W2[i];
    if (t < H2N) b2s[t] = b2[t];
    if (t < GR * 10){
        int r = t / 10, j = t - r * 10;
        h1s[r][j] = fast_sigmoid(x[rowblk + r] * W1[j] + b1[j]);
    }
    __syncthreads();
    #pragma unroll
    for (int k = 0; k < 4; ++k){
        int i = t + k * TPB;                 // 2048 = 16 x 128
        int r = i >> 7, c = i & 127;
        float v = 0.0f;
        if (c < H2N){
            float z = b2s[c];
            #pragma unroll
            for (int j = 0; j < 10; ++j) z += h1s[r][j] * w2s[j * H2N + c];
            v = fast_sigmoid(z);
        } else if (c == H2N) v = 1.0f;       // bias lane
        h2b[r][c] = f2bf(v);
    }
    __syncthreads();

    bf16x8 hfr[4];
    #pragma unroll
    for (int ks = 0; ks < 4; ++ks)
        hfr[ks] = *reinterpret_cast<const bf16x8*>(&h2b[lm][ks * 32 + lg * 8]);

    #define LOADFRAG(dst, tile) do {                                              \
        const unsigned short* bp_ = w3f + ((size_t)((tile) * 4) * 64 + lane) * 8; \
        _Pragma("unroll")                                                         \
        for (int ks_ = 0; ks_ < 4; ++ks_)                                         \
            dst[ks_] = *reinterpret_cast<const bf16x8*>(bp_ + (size_t)ks_ * 512); \
    } while(0)

    // ---- main tiles only: 77 slots over 8 waves, w3f read ONCE per block
    bf16x8 f1c[4], f1n[4];
    LOADFRAG(f1c, wid);
    for (int it = 0; it < 10; ++it){
        const int s  = wid + (it << 3);
        const int sn = s + 8;
        if (sn < NMAIN) LOADFRAG(f1n, sn);
        if (s < NMAIN){
            f32x4 a1 = {0,0,0,0};
            #pragma unroll
            for (int ks = 0; ks < 4; ++ks)
                a1 = __builtin_amdgcn_mfma_f32_16x16x32_bf16(f1c[ks], hfr[ks], a1, 0, 0, 0);
            unsigned short o[4];
            #pragma unroll
            for (int r = 0; r < 4; ++r) o[r] = f2bf(fast_sigmoid(a1[r]));
            *reinterpret_cast<u16x4*>(&panel[lm][(s << 4) + (lg << 2)]) =
                *reinterpret_cast<u16x4*>(o);
        }
        #pragma unroll
        for (int k2 = 0; k2 < 4; ++k2) f1c[k2] = f1n[k2];
    }
    __syncthreads();

    // ---- tail: lerp from the panel itself (c1,c2 < 1224 are main cols)
    for (int r = 0; r < GR; ++r){
        #pragma unroll
        for (int i = 0; i < 2; ++i){
            int p = t + i * TPB;
            if (p < TAILN){
                int c1 = (int)(tpk[i] & 0xffffu);
                int c2 = (int)(tpk[i] >> 16);
                float v1 = bf2f(panel[r][c1]);
                float v2 = bf2f(panel[r][c2]);
                panel[r][1232 + p] = f2bf(fmaf(tpw[i], v1 - v2, v2));
            }
        }
    }
    __syncthreads();

    // ---- dump: each wave writes 2 FULL rows, 8.7 KB contiguous each
    #pragma unroll
    for (int rr = 0; rr < 2; ++rr){
        const int row = (wid << 1) + rr;
        float* orow = out + (size_t)(rowblk + row) * OUTW;
        #pragma unroll
        for (int ch = 0; ch < 9; ++ch){
            const int rc = ch * 256 + (lane << 2);     // real col base (mult of 4)
            if (rc <= 2188){
                const int vc = rc + (rc >= N3 ? 8 : 0);
                const unsigned short* pp = &panel[row][vc];
                f32x4 v;
                #pragma unroll
                for (int e = 0; e < 4; ++e) v[e] = bf2f(pp[e]);
                store16(orow + rc, v);
            } else if (rc == 2192){
                orow[rc] = bf2f(panel[row][rc + 8]);
            }
        }
    }
    #undef LOADFRAG
}

extern "C" void kernel_launch(void* const* d_in, const int* in_sizes, int n_in,
                              void* d_out, int out_size, void* d_ws, size_t ws_size,
                              hipStream_t stream)
{
    const float* x   = (const float*)d_in[0];
    const float* W1  = (const float*)d_in[1];
    const float* b1  = (const float*)d_in[2];
    const float* W2  = (const float*)d_in[3];
    const float* b2  = (const float*)d_in[4];
    const float* W3  = (const float*)d_in[5];
    const float* b3  = (const float*)d_in[6];
    const float* wgt = (const float*)d_in[7];
    const int*   i1  = (const int*)d_in[8];
    const int*   i2  = (const int*)d_in[9];
    float* out = (float*)d_out;

    unsigned char* ws = (unsigned char*)d_ws;
    unsigned short* w3f = (unsigned short*)ws;                 // 77*4096 = 315,392 B
    unsigned int*   pk  = (unsigned int*)(ws + 315392);        // 3,876 B (pad 3,904)
    float*          pw  = (float*)(ws + 315392 + 3904);        // 3,876 B

    prep_kernel<<<NMAIN + 4, 256, 0, stream>>>(W3, b3, wgt, i1, i2, w3f, pk, pw);
    snn_kernel<<<NBLK, TPB, 0, stream>>>(x, W1, b1, W2, b2, w3f, pk, pw, out);
}

// Round 15
// 149.633 us; speedup vs baseline: 3.7359x; 1.0055x over previous
//
#include <hip/hip_runtime.h>
#include <hip/hip_bf16.h>
#include <stdint.h>

#define NROWS   65536
#define GR      16                // rows per block
#define NBLK    (NROWS/GR)        // 4096
#define TPB     512
#define H2N     100
#define KPAD    128
#define N3      1224
#define OUTW    2193
#define TAILN   969
#define NMAIN   77                // main tiles only in w3f
#define PSTRC   2212              // panel row stride (shorts)

typedef __attribute__((ext_vector_type(8))) short bf16x8;
typedef __attribute__((ext_vector_type(4))) float f32x4;
typedef __attribute__((ext_vector_type(4))) unsigned short u16x4;
typedef __attribute__((ext_vector_type(4))) unsigned int u32x4;

__device__ __forceinline__ float fast_sigmoid(float z){
    return __builtin_amdgcn_rcpf(1.0f + __expf(-z));
}
__device__ __forceinline__ unsigned short f2bf(float v){
    __hip_bfloat16 h = __float2bfloat16(v);
    return *reinterpret_cast<unsigned short*>(&h);
}
__device__ __forceinline__ float bf2f(unsigned short u){
    return __uint_as_float(((unsigned)u) << 16);
}
__device__ __forceinline__ void store16(float* p, f32x4 v){
    __builtin_memcpy(p, &v, 16);
}

// blocks 0..76: w3f[((t*4+ks)*64+lane)*8+e] = bf16(W3[k][t*16+lm]), b3 folded at k==100.
// blocks 77..80: tail tables pk[p]=(c2<<16)|c1, pw[p]=w[j].
__global__ void prep_kernel(const float* __restrict__ W3,
                            const float* __restrict__ b3,
                            const float* __restrict__ wgt,
                            const int* __restrict__ idx1,
                            const int* __restrict__ idx2,
                            unsigned short* __restrict__ w3f,
                            unsigned int* __restrict__ pk,
                            float* __restrict__ pw){
    const int blk = blockIdx.x;
    if (blk < NMAIN){
        const int ks   = threadIdx.x >> 6;
        const int lane = threadIdx.x & 63;
        const int lm   = lane & 15, lgf = lane >> 4;
        const int c    = blk * 16 + lm;
        const bool ok  = (c < N3);

        unsigned short vals[8];
        #pragma unroll
        for (int e = 0; e < 8; ++e){
            int k = ks * 32 + lgf * 8 + e;
            float v = 0.0f;
            if (ok){
                if (k < H2N)       v = W3[k * N3 + c];
                else if (k == H2N) v = b3[c];          // bias folded into K
            }
            vals[e] = f2bf(v);
        }
        *reinterpret_cast<bf16x8*>(w3f + ((size_t)(blk * 4 + ks) * 64 + lane) * 8)
            = *reinterpret_cast<bf16x8*>(vals);
    } else {
        const int p = (blk - NMAIN) * 256 + threadIdx.x;
        if (p < 976){
            if (p < TAILN){
                int j = p / 17, k = p - j * 17;
                unsigned int c1 = (unsigned)(idx1[j] * 17 + k);
                unsigned int c2 = (unsigned)(idx2[j] * 17 + k);
                pk[p] = (c2 << 16) | c1;
                pw[p] = wgt[j];
            } else {            // pad quads: safe values
                pk[p] = 0;
                pw[p] = 0.0f;
            }
        }
    }
}

__global__ __launch_bounds__(TPB, 4)
void snn_kernel(const float* __restrict__ x,
                const float* __restrict__ W1, const float* __restrict__ b1,
                const float* __restrict__ W2, const float* __restrict__ b2,
                const unsigned short* __restrict__ w3f,
                const unsigned int* __restrict__ pk,
                const float* __restrict__ pw,
                float* __restrict__ out)
{
    __shared__ __align__(16) unsigned short panel[GR][PSTRC];   // 70.8 KB
    __shared__ __align__(16) unsigned short h2b[GR][KPAD];      // 4 KB
    __shared__ float h1s[GR][10];                               // 640 B
    __shared__ float w2s[H2N * 10];                             // 4 KB
    __shared__ float b2s[H2N];                                  // 400 B

    const int t = threadIdx.x, lane = t & 63, wid = t >> 6;     // 8 waves
    const int lm = lane & 15, lg = lane >> 4;
    const unsigned int rowblk = blockIdx.x * GR;

    // ---- prologue: stage W2/b2, compute h1, h2 (k=100 bias lane = 1.0)
    for (int i = t; i < H2N * 10; i += TPB) w2s[i] = W2[i];
    if (t < H2N) b2s[t] = b2[t];
    if (t < GR * 10){
        int r = t / 10, j = t - r * 10;
        h1s[r][j] = fast_sigmoid(x[rowblk + r] * W1[j] + b1[j]);
    }
    __syncthreads();
    #pragma unroll
    for (int k = 0; k < 4; ++k){
        int i = t + k * TPB;                 // 2048 = 16 x 128
        int r = i >> 7, c = i & 127;
        float v = 0.0f;
        if (c < H2N){
            float z = b2s[c];
            #pragma unroll
            for (int j = 0; j < 10; ++j) z += h1s[r][j] * w2s[j * H2N + c];
            v = fast_sigmoid(z);
        } else if (c == H2N) v = 1.0f;       // bias lane
        h2b[r][c] = f2bf(v);
    }
    __syncthreads();

    bf16x8 hfr[4];
    #pragma unroll
    for (int ks = 0; ks < 4; ++ks)
        hfr[ks] = *reinterpret_cast<const bf16x8*>(&h2b[lm][ks * 32 + lg * 8]);

    #define LOADFRAG(dst, tile) do {                                              \
        const unsigned short* bp_ = w3f + ((size_t)((tile) * 4) * 64 + lane) * 8; \
        _Pragma("unroll")                                                         \
        for (int ks_ = 0; ks_ < 4; ++ks_)                                         \
            dst[ks_] = *reinterpret_cast<const bf16x8*>(bp_ + (size_t)ks_ * 512); \
    } while(0)

    // ---- main tiles: 77 slots over 8 waves, w3f read ONCE per block
    bf16x8 f1c[4], f1n[4];
    LOADFRAG(f1c, wid);
    for (int it = 0; it < 10; ++it){
        const int s  = wid + (it << 3);
        const int sn = s + 8;
        if (sn < NMAIN) LOADFRAG(f1n, sn);
        if (s < NMAIN){
            f32x4 a1 = {0,0,0,0};
            #pragma unroll
            for (int ks = 0; ks < 4; ++ks)
                a1 = __builtin_amdgcn_mfma_f32_16x16x32_bf16(f1c[ks], hfr[ks], a1, 0, 0, 0);
            unsigned short o[4];
            #pragma unroll
            for (int r = 0; r < 4; ++r) o[r] = f2bf(fast_sigmoid(a1[r]));
            *reinterpret_cast<u16x4*>(&panel[lm][(s << 4) + (lg << 2)]) =
                *reinterpret_cast<u16x4*>(o);
        }
        #pragma unroll
        for (int k2 = 0; k2 < 4; ++k2) f1c[k2] = f1n[k2];
    }
    __syncthreads();

    // ---- tail: quad-parallel lerp from the panel (c1,c2 < 1224 are main cols)
    // q = t + 512*i -> row = q>>8, quad = q&255 (243 real quads/row); 8 indep iters
    #pragma unroll 2
    for (int i = 0; i < 8; ++i){
        const int q  = t + (i << 9);
        const int r  = q >> 8;
        const int p0 = (q & 255) << 2;
        if (p0 < TAILN){
            const u32x4 k4 = *reinterpret_cast<const u32x4*>(&pk[p0]);
            const f32x4 w4 = *reinterpret_cast<const f32x4*>(&pw[p0]);
            unsigned short o[4];
            #pragma unroll
            for (int e = 0; e < 4; ++e){
                if (p0 + e < TAILN){
                    const int c1 = (int)(k4[e] & 0xffffu);
                    const int c2 = (int)(k4[e] >> 16);
                    const float v2 = bf2f(panel[r][c2]);
                    o[e] = f2bf(fmaf(w4[e], bf2f(panel[r][c1]) - v2, v2));
                } else o[e] = 0;
            }
            *reinterpret_cast<u16x4*>(&panel[r][1232 + p0]) =
                *reinterpret_cast<u16x4*>(o);
        }
    }
    __syncthreads();

    // ---- dump: each wave writes 2 FULL rows, 8.7 KB contiguous each (b64 LDS reads)
    #pragma unroll
    for (int rr = 0; rr < 2; ++rr){
        const int row = (wid << 1) + rr;
        float* orow = out + (size_t)(rowblk + row) * OUTW;
        #pragma unroll
        for (int ch = 0; ch < 9; ++ch){
            const int rc = ch * 256 + (lane << 2);     // real col base (mult of 4)
            if (rc <= 2188){
                const int vc = rc + (rc >= N3 ? 8 : 0);
                const u16x4 pv = *reinterpret_cast<const u16x4*>(&panel[row][vc]);
                f32x4 v;
                #pragma unroll
                for (int e = 0; e < 4; ++e) v[e] = bf2f(pv[e]);
                store16(orow + rc, v);
            } else if (rc == 2192){
                orow[rc] = bf2f(panel[row][rc + 8]);
            }
        }
    }
    #undef LOADFRAG
}

extern "C" void kernel_launch(void* const* d_in, const int* in_sizes, int n_in,
                              void* d_out, int out_size, void* d_ws, size_t ws_size,
                              hipStream_t stream)
{
    const float* x   = (const float*)d_in[0];
    const float* W1  = (const float*)d_in[1];
    const float* b1  = (const float*)d_in[2];
    const float* W2  = (const float*)d_in[3];
    const float* b2  = (const float*)d_in[4];
    const float* W3  = (const float*)d_in[5];
    const float* b3  = (const float*)d_in[6];
    const float* wgt = (const float*)d_in[7];
    const int*   i1  = (const int*)d_in[8];
    const int*   i2  = (const int*)d_in[9];
    float* out = (float*)d_out;

    unsigned char* ws = (unsigned char*)d_ws;
    unsigned short* w3f = (unsigned short*)ws;                 // 77*4096 = 315,392 B
    unsigned int*   pk  = (unsigned int*)(ws + 315392);        // 976*4 = 3,904 B
    float*          pw  = (float*)(ws + 315392 + 3904);        // 976*4 = 3,904 B

    prep_kernel<<<NMAIN + 4, 256, 0, stream>>>(W3, b3, wgt, i1, i2, w3f, pk, pw);
    snn_kernel<<<NBLK, TPB, 0, stream>>>(x, W1, b1, W2, b2, w3f, pk, pw, out);
}

// Round 16
// 135.933 us; speedup vs baseline: 4.1124x; 1.1008x over previous
//
#include <hip/hip_runtime.h>
#include <hip/hip_bf16.h>
#include <stdint.h>

#define NROWS   65536
#define GR      16                // rows per group
#define NGRP    16                // groups per block
#define RPB     (GR*NGRP)         // 256 rows per block
#define NBLK    (NROWS/RPB)       // 256 blocks = 1 per CU (LDS-guaranteed)
#define TPB     1024
#define H2N     100
#define KPAD    128
#define N3      1224
#define OUTW    2193
#define TAILN   969
#define NMAIN   77
#define PSTRC   2212              // panel row stride (shorts); 553 dwords, odd mod 32

typedef __attribute__((ext_vector_type(8))) short bf16x8;
typedef __attribute__((ext_vector_type(4))) float f32x4;
typedef __attribute__((ext_vector_type(4))) unsigned short u16x4;
typedef __attribute__((ext_vector_type(4))) unsigned int u32x4;

__device__ __forceinline__ float fast_sigmoid(float z){
    return __builtin_amdgcn_rcpf(1.0f + __expf(-z));
}
__device__ __forceinline__ unsigned short f2bf(float v){
    __hip_bfloat16 h = __float2bfloat16(v);
    return *reinterpret_cast<unsigned short*>(&h);
}
__device__ __forceinline__ float bf2f(unsigned short u){
    return __uint_as_float(((unsigned)u) << 16);
}
__device__ __forceinline__ void store16(float* p, f32x4 v){
    __builtin_memcpy(p, &v, 16);
}

// raw barrier: LDS-order only — does NOT drain outstanding global stores
#define BAR() do { asm volatile("s_waitcnt lgkmcnt(0)" ::: "memory");  \
                   __builtin_amdgcn_s_barrier();                        \
                   __builtin_amdgcn_sched_barrier(0); } while(0)

// blocks 0..76: w3f[((t*4+ks)*64+lane)*8+e] = bf16(W3[k][t*16+lm]), b3 folded at k==100.
// blocks 77..80: tail tables pk[p]=(c2<<16)|c1, pw[p]=w[j] (padded to 976).
__global__ void prep_kernel(const float* __restrict__ W3,
                            const float* __restrict__ b3,
                            const float* __restrict__ wgt,
                            const int* __restrict__ idx1,
                            const int* __restrict__ idx2,
                            unsigned short* __restrict__ w3f,
                            unsigned int* __restrict__ pk,
                            float* __restrict__ pw){
    const int blk = blockIdx.x;
    if (blk < NMAIN){
        const int ks   = threadIdx.x >> 6;
        const int lane = threadIdx.x & 63;
        const int lm   = lane & 15, lgf = lane >> 4;
        const int c    = blk * 16 + lm;
        const bool ok  = (c < N3);

        unsigned short vals[8];
        #pragma unroll
        for (int e = 0; e < 8; ++e){
            int k = ks * 32 + lgf * 8 + e;
            float v = 0.0f;
            if (ok){
                if (k < H2N)       v = W3[k * N3 + c];
                else if (k == H2N) v = b3[c];          // bias folded into K
            }
            vals[e] = f2bf(v);
        }
        *reinterpret_cast<bf16x8*>(w3f + ((size_t)(blk * 4 + ks) * 64 + lane) * 8)
            = *reinterpret_cast<bf16x8*>(vals);
    } else {
        const int p = (blk - NMAIN) * 256 + threadIdx.x;
        if (p < 976){
            if (p < TAILN){
                int j = p / 17, k = p - j * 17;
                pk[p] = ((unsigned)(idx2[j] * 17 + k) << 16) | (unsigned)(idx1[j] * 17 + k);
                pw[p] = wgt[j];
            } else { pk[p] = 0; pw[p] = 0.0f; }
        }
    }
}

__global__ __launch_bounds__(TPB, 4)
void snn_kernel(const float* __restrict__ x,
                const float* __restrict__ W1, const float* __restrict__ b1,
                const float* __restrict__ W2, const float* __restrict__ b2,
                const unsigned short* __restrict__ w3f,
                const unsigned int* __restrict__ pk,
                const float* __restrict__ pw,
                float* __restrict__ out)
{
    __shared__ __align__(16) unsigned short panel[GR][PSTRC];   // 70,784 B
    __shared__ __align__(16) unsigned short h2b[GR][KPAD];      //  4,096 B
    __shared__ float w2s[H2N * 10];                             //  4,000 B
    __shared__ float b2s[H2N];                                  //    400 B
    __shared__ float h1s[GR][10];                               //    640 B
    __shared__ float xs[RPB];                                   //  1,024 B
    __shared__ float w1s[10], b1s[10];                          //     80 B
    __shared__ __align__(16) unsigned int pks[976];             //  3,904 B
    __shared__ __align__(16) float        pws[976];             //  3,904 B
    // total ~88.8 KB -> exactly 1 block/CU

    const int t = threadIdx.x, lane = t & 63, wid = t >> 6;     // 16 waves
    const int lm = lane & 15, lg = lane >> 4;
    const unsigned int rowblk0 = blockIdx.x * RPB;

    #define LOADFRAG(dst, tile) do {                                              \
        const unsigned short* bp_ = w3f + ((size_t)((tile) * 4) * 64 + lane) * 8; \
        _Pragma("unroll")                                                         \
        for (int ks_ = 0; ks_ < 4; ++ks_)                                         \
            dst[ks_] = *reinterpret_cast<const bf16x8*>(bp_ + (size_t)ks_ * 512); \
    } while(0)

    // ---- prologue: stage EVERYTHING (the only global loads in this kernel)
    for (int i = t; i < H2N * 10; i += TPB) w2s[i] = W2[i];
    if (t < H2N) b2s[t] = b2[t];
    if (t < 10){ w1s[t] = W1[t]; b1s[t] = b1[t]; }
    if (t < RPB) xs[t] = x[rowblk0 + t];
    if (t < 976){ pks[t] = pk[t]; pws[t] = pw[t]; }

    bf16x8 wfr[5][4];                       // W3 frags resident: 5 slots/wave max
    #pragma unroll
    for (int i = 0; i < 5; ++i){
        const int s = wid + (i << 4);
        if (s < NMAIN) LOADFRAG(wfr[i], s);
    }
    __syncthreads();                        // full sync once (drains prologue loads)

    // ---- 16-group steady state: zero global loads, raw barriers, streaming stores
    for (int g = 0; g < NGRP; ++g){
        // p1: h1(g)
        if (t < GR * 10){
            const int r = t / 10, j = t - r * 10;
            h1s[r][j] = fast_sigmoid(xs[(g << 4) + r] * w1s[j] + b1s[j]);
        }
        BAR();
        // p2: h2(g) (k=100 bias lane = 1.0)
        #pragma unroll
        for (int ii = 0; ii < 2; ++ii){
            const int i = t + ii * TPB;
            const int r = i >> 7, c = i & 127;
            float v = 0.0f;
            if (c < H2N){
                float z = b2s[c];
                #pragma unroll
                for (int j = 0; j < 10; ++j) z += h1s[r][j] * w2s[j * H2N + c];
                v = fast_sigmoid(z);
            } else if (c == H2N) v = 1.0f;
            h2b[r][c] = f2bf(v);
        }
        BAR();
        // p3: MFMA from register-resident W3 frags -> panel
        {
            bf16x8 hfr[4];
            #pragma unroll
            for (int ks = 0; ks < 4; ++ks)
                hfr[ks] = *reinterpret_cast<const bf16x8*>(&h2b[lm][ks * 32 + lg * 8]);
            #pragma unroll
            for (int i = 0; i < 5; ++i){
                const int s = wid + (i << 4);
                if (s < NMAIN){
                    f32x4 a = {0,0,0,0};
                    #pragma unroll
                    for (int ks = 0; ks < 4; ++ks)
                        a = __builtin_amdgcn_mfma_f32_16x16x32_bf16(wfr[i][ks], hfr[ks], a, 0, 0, 0);
                    unsigned short o[4];
                    #pragma unroll
                    for (int r = 0; r < 4; ++r) o[r] = f2bf(fast_sigmoid(a[r]));
                    *reinterpret_cast<u16x4*>(&panel[lm][(s << 4) + (lg << 2)]) =
                        *reinterpret_cast<u16x4*>(o);
                }
            }
        }
        BAR();
        // p4: tail lerp within panel (c1,c2 are main cols)
        #pragma unroll
        for (int i = 0; i < 4; ++i){
            const int q  = t + (i << 10);
            const int r  = q >> 8;
            const int p0 = (q & 255) << 2;
            if (p0 < TAILN){
                const u32x4 k4 = *reinterpret_cast<const u32x4*>(&pks[p0]);
                const f32x4 w4 = *reinterpret_cast<const f32x4*>(&pws[p0]);
                unsigned short o[4];
                #pragma unroll
                for (int e = 0; e < 4; ++e){
                    if (p0 + e < TAILN){
                        const int c1 = (int)(k4[e] & 0xffffu);
                        const int c2 = (int)(k4[e] >> 16);
                        const float v2 = bf2f(panel[r][c2]);
                        o[e] = f2bf(fmaf(w4[e], bf2f(panel[r][c1]) - v2, v2));
                    } else o[e] = 0;
                }
                *reinterpret_cast<u16x4*>(&panel[r][1232 + p0]) =
                    *reinterpret_cast<u16x4*>(o);
            }
        }
        BAR();
        // p5: dump — wave wid streams its full row; stores stay in flight
        {
            const int row = wid;
            float* orow = out + (size_t)(rowblk0 + (g << 4) + row) * OUTW;
            #pragma unroll
            for (int ch = 0; ch < 9; ++ch){
                const int rc = ch * 256 + (lane << 2);
                if (rc <= 2188){
                    const int vc = rc + (rc >= N3 ? 8 : 0);
                    const u16x4 pv = *reinterpret_cast<const u16x4*>(&panel[row][vc]);
                    f32x4 v;
                    #pragma unroll
                    for (int e = 0; e < 4; ++e) v[e] = bf2f(pv[e]);
                    store16(orow + rc, v);
                } else if (rc == 2192){
                    orow[rc] = bf2f(panel[row][rc + 8]);
                }
            }
        }
        // no barrier here: next group's p1 barrier (lgkm-only) orders panel reuse
    }
    #undef LOADFRAG
}

extern "C" void kernel_launch(void* const* d_in, const int* in_sizes, int n_in,
                              void* d_out, int out_size, void* d_ws, size_t ws_size,
                              hipStream_t stream)
{
    const float* x   = (const float*)d_in[0];
    const float* W1  = (const float*)d_in[1];
    const float* b1  = (const float*)d_in[2];
    const float* W2  = (const float*)d_in[3];
    const float* b2  = (const float*)d_in[4];
    const float* W3  = (const float*)d_in[5];
    const float* b3  = (const float*)d_in[6];
    const float* wgt = (const float*)d_in[7];
    const int*   i1  = (const int*)d_in[8];
    const int*   i2  = (const int*)d_in[9];
    float* out = (float*)d_out;

    unsigned char* ws = (unsigned char*)d_ws;
    unsigned short* w3f = (unsigned short*)ws;                 // 315,392 B
    unsigned int*   pk  = (unsigned int*)(ws + 315392);        // 3,904 B
    float*          pw  = (float*)(ws + 315392 + 3904);        // 3,904 B

    prep_kernel<<<NMAIN + 4, 256, 0, stream>>>(W3, b3, wgt, i1, i2, w3f, pk, pw);
    snn_kernel<<<NBLK, TPB, 0, stream>>>(x, W1, b1, W2, b2, w3f, pk, pw, out);
}

// Round 17
// 126.020 us; speedup vs baseline: 4.4359x; 1.0787x over previous
//
#include <hip/hip_runtime.h>
#include <hip/hip_bf16.h>
#include <stdint.h>

#define NROWS   65536
#define GR      16                // rows per group
#define NGRP    16                // groups per block
#define RPB     (GR*NGRP)         // 256 rows per block
#define NBLK    (NROWS/RPB)       // 256 blocks = 1 per CU
#define TPB     1024
#define H2N     100
#define KPAD    128
#define N3      1224
#define OUTW    2193
#define TAILN   969
#define NMAIN   77
#define PSTRC   2212              // panel row stride (shorts)

typedef __attribute__((ext_vector_type(8))) short bf16x8;
typedef __attribute__((ext_vector_type(4))) float f32x4;
typedef __attribute__((ext_vector_type(4))) unsigned short u16x4;

__device__ __forceinline__ float fast_sigmoid(float z){
    return __builtin_amdgcn_rcpf(1.0f + __expf(-z));
}
__device__ __forceinline__ unsigned short f2bf(float v){
    __hip_bfloat16 h = __float2bfloat16(v);
    return *reinterpret_cast<unsigned short*>(&h);
}
__device__ __forceinline__ float bf2f(unsigned short u){
    return __uint_as_float(((unsigned)u) << 16);
}
__device__ __forceinline__ void store16(float* p, f32x4 v){
    __builtin_memcpy(p, &v, 16);
}

// raw barrier: LDS-order only — does NOT drain outstanding global stores
#define BAR() do { asm volatile("s_waitcnt lgkmcnt(0)" ::: "memory");  \
                   __builtin_amdgcn_s_barrier();                        \
                   __builtin_amdgcn_sched_barrier(0); } while(0)

// blocks 0..76: w3f[((t*4+ks)*64+lane)*8+e] = bf16(W3[k][t*16+lm]), b3 folded at k==100.
// blocks 77..80: tail tables pk[p]=(c2<<16)|c1, pw[p]=w[j] (padded to 976).
__global__ void prep_kernel(const float* __restrict__ W3,
                            const float* __restrict__ b3,
                            const float* __restrict__ wgt,
                            const int* __restrict__ idx1,
                            const int* __restrict__ idx2,
                            unsigned short* __restrict__ w3f,
                            unsigned int* __restrict__ pk,
                            float* __restrict__ pw){
    const int blk = blockIdx.x;
    if (blk < NMAIN){
        const int ks   = threadIdx.x >> 6;
        const int lane = threadIdx.x & 63;
        const int lm   = lane & 15, lgf = lane >> 4;
        const int c    = blk * 16 + lm;
        const bool ok  = (c < N3);

        unsigned short vals[8];
        #pragma unroll
        for (int e = 0; e < 8; ++e){
            int k = ks * 32 + lgf * 8 + e;
            float v = 0.0f;
            if (ok){
                if (k < H2N)       v = W3[k * N3 + c];
                else if (k == H2N) v = b3[c];          // bias folded into K
            }
            vals[e] = f2bf(v);
        }
        *reinterpret_cast<bf16x8*>(w3f + ((size_t)(blk * 4 + ks) * 64 + lane) * 8)
            = *reinterpret_cast<bf16x8*>(vals);
    } else {
        const int p = (blk - NMAIN) * 256 + threadIdx.x;
        if (p < 976){
            if (p < TAILN){
                int j = p / 17, k = p - j * 17;
                pk[p] = ((unsigned)(idx2[j] * 17 + k) << 16) | (unsigned)(idx1[j] * 17 + k);
                pw[p] = wgt[j];
            } else { pk[p] = 0; pw[p] = 0.0f; }
        }
    }
}

__global__ __launch_bounds__(TPB, 4)
void snn_kernel(const float* __restrict__ x,
                const float* __restrict__ W1, const float* __restrict__ b1,
                const float* __restrict__ W2, const float* __restrict__ b2,
                const unsigned short* __restrict__ w3f,
                const unsigned int* __restrict__ pk,
                const float* __restrict__ pw,
                float* __restrict__ out)
{
    __shared__ __align__(16) unsigned short panel[GR][PSTRC];   // 70,784 B
    __shared__ __align__(16) unsigned short h2b[GR][KPAD];      //  4,096 B
    __shared__ float w2s[H2N * 10];                             //  4,000 B
    __shared__ float b2s[H2N];                                  //    400 B
    __shared__ float xs[RPB];                                   //  1,024 B
    __shared__ float w1s[10], b1s[10];                          //     80 B
    __shared__ __align__(16) unsigned int pks[976];             //  3,904 B
    __shared__ __align__(16) float        pws[976];             //  3,904 B
    // total ~86.1 KB -> 1 block/CU

    const int t = threadIdx.x, lane = t & 63, wid = t >> 6;     // 16 waves
    const int lm = lane & 15, lg = lane >> 4;
    const unsigned int rowblk0 = blockIdx.x * RPB;

    #define LOADFRAG(dst, tile) do {                                              \
        const unsigned short* bp_ = w3f + ((size_t)((tile) * 4) * 64 + lane) * 8; \
        _Pragma("unroll")                                                         \
        for (int ks_ = 0; ks_ < 4; ++ks_)                                         \
            dst[ks_] = *reinterpret_cast<const bf16x8*>(bp_ + (size_t)ks_ * 512); \
    } while(0)

    // ---- prologue: stage EVERYTHING (the only global loads in this kernel)
    for (int i = t; i < H2N * 10; i += TPB) w2s[i] = W2[i];
    if (t < H2N) b2s[t] = b2[t];
    if (t < 10){ w1s[t] = W1[t]; b1s[t] = b1[t]; }
    if (t < RPB) xs[t] = x[rowblk0 + t];
    if (t < 976){ pks[t] = pk[t]; pws[t] = pw[t]; }

    bf16x8 wfr[5][4];                       // W3 frags resident (80 VGPR)
    #pragma unroll
    for (int i = 0; i < 5; ++i){
        const int s = wid + (i << 4);
        if (s < NMAIN) LOADFRAG(wfr[i], s);
    }
    __syncthreads();                        // one full sync (drains prologue loads)

    // ---- 16-group steady state: 2 raw barriers/group, zero global loads
    for (int g = 0; g < NGRP; ++g){
        // ---- A: fused h1+h2 — thread owns (row r, cols c0,c0+1); no intra-phase sync
        {
            const int r  = t >> 6;
            const int c0 = (t & 63) << 1;
            const float xr = xs[(g << 4) + r];
            float h1v[10];
            #pragma unroll
            for (int j = 0; j < 10; ++j)
                h1v[j] = fast_sigmoid(xr * w1s[j] + b1s[j]);
            unsigned short o0, o1;
            if (c0 < H2N){
                float z = b2s[c0];
                #pragma unroll
                for (int j = 0; j < 10; ++j) z += h1v[j] * w2s[j * H2N + c0];
                o0 = f2bf(fast_sigmoid(z));
            } else o0 = (c0 == H2N) ? 0x3F80 : 0;          // 1.0 bias lane / zero pad
            const int c1 = c0 + 1;
            if (c1 < H2N){
                float z = b2s[c1];
                #pragma unroll
                for (int j = 0; j < 10; ++j) z += h1v[j] * w2s[j * H2N + c1];
                o1 = f2bf(fast_sigmoid(z));
            } else o1 = (c1 == H2N) ? 0x3F80 : 0;
            unsigned int packed = (unsigned)o0 | ((unsigned)o1 << 16);
            *reinterpret_cast<unsigned int*>(&h2b[r][c0]) = packed;
        }
        BAR();                                             // BAR1: h2 ready
        // ---- B: MFMA from register-resident W3 frags -> panel
        {
            bf16x8 hfr[4];
            #pragma unroll
            for (int ks = 0; ks < 4; ++ks)
                hfr[ks] = *reinterpret_cast<const bf16x8*>(&h2b[lm][ks * 32 + lg * 8]);
            #pragma unroll
            for (int i = 0; i < 5; ++i){
                const int s = wid + (i << 4);
                if (s < NMAIN){
                    f32x4 a = {0,0,0,0};
                    #pragma unroll
                    for (int ks = 0; ks < 4; ++ks)
                        a = __builtin_amdgcn_mfma_f32_16x16x32_bf16(wfr[i][ks], hfr[ks], a, 0, 0, 0);
                    unsigned short o[4];
                    #pragma unroll
                    for (int r = 0; r < 4; ++r) o[r] = f2bf(fast_sigmoid(a[r]));
                    *reinterpret_cast<u16x4*>(&panel[lm][(s << 4) + (lg << 2)]) =
                        *reinterpret_cast<u16x4*>(o);
                }
            }
        }
        BAR();                                             // BAR2: panel main cols ready
        // ---- C: per-wave row = wid — tail lerp into panel, then dump the row.
        //      Wave-local row ownership: no barrier needed between lerp and dump.
        {
            const int row = wid;
            #pragma unroll
            for (int i = 0; i < 8; ++i){
                const int p0 = (lane + (i << 6)) << 1;     // even p, pairs (p0, p0+1)
                if (p0 < TAILN){
                    const unsigned int k0 = pks[p0], k1 = pks[p0 + 1];
                    const float w0 = pws[p0], w1 = pws[p0 + 1];
                    const float a2 = bf2f(panel[row][k0 >> 16]);
                    const float a1 = bf2f(panel[row][k0 & 0xffffu]);
                    const float b2v = bf2f(panel[row][k1 >> 16]);
                    const float b1v = bf2f(panel[row][k1 & 0xffffu]);
                    const unsigned short t0 = f2bf(fmaf(w0, a1 - a2, a2));
                    const unsigned short t1 = f2bf(fmaf(w1, b1v - b2v, b2v));
                    *reinterpret_cast<unsigned int*>(&panel[row][1232 + p0]) =
                        (unsigned)t0 | ((unsigned)t1 << 16);
                }
            }
            float* orow = out + (size_t)(rowblk0 + (g << 4) + row) * OUTW;
            #pragma unroll
            for (int ch = 0; ch < 9; ++ch){
                const int rc = ch * 256 + (lane << 2);
                if (rc <= 2188){
                    const int vc = rc + (rc >= N3 ? 8 : 0);
                    const u16x4 pv = *reinterpret_cast<const u16x4*>(&panel[row][vc]);
                    f32x4 v;
                    #pragma unroll
                    for (int e = 0; e < 4; ++e) v[e] = bf2f(pv[e]);
                    store16(orow + rc, v);
                } else if (rc == 2192){
                    orow[rc] = bf2f(panel[row][rc + 8]);
                }
            }
        }
        // no barrier: next A writes h2b (safe after BAR2); next B waits BAR1'
    }
    #undef LOADFRAG
}

extern "C" void kernel_launch(void* const* d_in, const int* in_sizes, int n_in,
                              void* d_out, int out_size, void* d_ws, size_t ws_size,
                              hipStream_t stream)
{
    const float* x   = (const float*)d_in[0];
    const float* W1  = (const float*)d_in[1];
    const float* b1  = (const float*)d_in[2];
    const float* W2  = (const float*)d_in[3];
    const float* b2  = (const float*)d_in[4];
    const float* W3  = (const float*)d_in[5];
    const float* b3  = (const float*)d_in[6];
    const float* wgt = (const float*)d_in[7];
    const int*   i1  = (const int*)d_in[8];
    const int*   i2  = (const int*)d_in[9];
    float* out = (float*)d_out;

    unsigned char* ws = (unsigned char*)d_ws;
    unsigned short* w3f = (unsigned short*)ws;                 // 315,392 B
    unsigned int*   pk  = (unsigned int*)(ws + 315392);        // 3,904 B
    float*          pw  = (float*)(ws + 315392 + 3904);        // 3,904 B

    prep_kernel<<<NMAIN + 4, 256, 0, stream>>>(W3, b3, wgt, i1, i2, w3f, pk, pw);
    snn_kernel<<<NBLK, TPB, 0, stream>>>(x, W1, b1, W2, b2, w3f, pk, pw, out);
}